// Round 1
// baseline (345.061 us; speedup 1.0000x reference)
//
#include <hip/hip_runtime.h>
#include <hip/hip_bf16.h>

#define SEQ 2048
#define DIMH 64
#define QB 64
#define KB 64
#define NW 4

typedef __attribute__((ext_vector_type(8))) short bf16x8;
typedef __attribute__((ext_vector_type(4))) float f32x4;

__device__ inline unsigned short f2bf(float f) {
    union { float f; unsigned u; } c; c.f = f;
    unsigned u = c.u;
    return (unsigned short)((u + 0x7FFFu + ((u >> 16) & 1u)) >> 16);
}

// swizzled element index within a [rows][64] ushort tile:
// byte ^= (row&7)<<4  ==  elem col ^= (row&7)<<3   (Guideline 4)
__device__ inline int swz(int row, int col) {
    return row * 64 + (col ^ ((row & 7) << 3));
}

__global__ __launch_bounds__(256, 2) void fattn(
    const float* __restrict__ Q, const float* __restrict__ K,
    const float* __restrict__ V, float* __restrict__ O)
{
    __shared__ __align__(16) unsigned short Ksh[KB * DIMH];      // [kv][dim], swizzled
    __shared__ __align__(16) unsigned short Vt[DIMH * KB];       // [dim][kv], swizzled
    __shared__ __align__(16) unsigned short Psh[NW * 16 * KB];   // per-wave [qrow][kv], swizzled

    const int tid  = threadIdx.x;
    const int lane = tid & 63;
    const int wv   = tid >> 6;
    const int bh   = blockIdx.x >> 5;   // 32 q-tiles per head
    const int qt   = blockIdx.x & 31;

    const int l15 = lane & 15;
    const int lg  = lane >> 4;          // 0..3

    const float* qh = Q + (size_t)bh * SEQ * DIMH;
    const float* kh = K + (size_t)bh * SEQ * DIMH;
    const float* vh = V + (size_t)bh * SEQ * DIMH;
    float*       oh = O + (size_t)bh * SEQ * DIMH;

    const int q0 = qt * QB + wv * 16;   // this wave's first q row

    // Q fragments, pre-scaled by 1/8 (exact, power of two).
    // A-layout: A[row=l15][k = ks*32 + lg*8 + j]
    bf16x8 qf[2];
    #pragma unroll
    for (int ks = 0; ks < 2; ++ks) {
        const float* src = qh + (size_t)(q0 + l15) * DIMH + ks * 32 + lg * 8;
        bf16x8 vq;
        #pragma unroll
        for (int j = 0; j < 8; ++j) vq[j] = (short)f2bf(src[j] * 0.125f);
        qf[ks] = vq;
    }

    f32x4 oacc[4] = {{0.f,0.f,0.f,0.f},{0.f,0.f,0.f,0.f},
                     {0.f,0.f,0.f,0.f},{0.f,0.f,0.f,0.f}};
    float mrow[4], lrow[4];
    #pragma unroll
    for (int r = 0; r < 4; ++r) { mrow[r] = -1e30f; lrow[r] = 0.f; }

    unsigned short* pw = &Psh[wv * 16 * 64];

    for (int kt = 0; kt < SEQ / KB; ++kt) {
        __syncthreads();   // previous iter's reads of Ksh/Vt done
        // ---- stage K [kv][dim] and V^T [dim][kv] (fp32 -> bf16 via regs) ----
        {
            const int c4 = (tid & 15) * 4;       // dim base
            #pragma unroll
            for (int rr = 0; rr < 4; ++rr) {
                const int row = rr * 16 + (tid >> 4);  // kv row in tile
                const size_t gofs = (size_t)(kt * KB + row) * DIMH + c4;
                const float4 k4 = *reinterpret_cast<const float4*>(kh + gofs);
                unsigned kw0 = (unsigned)f2bf(k4.x) | ((unsigned)f2bf(k4.y) << 16);
                unsigned kw1 = (unsigned)f2bf(k4.z) | ((unsigned)f2bf(k4.w) << 16);
                uint2 kk; kk.x = kw0; kk.y = kw1;
                *reinterpret_cast<uint2*>(&Ksh[swz(row, c4)]) = kk;

                const float4 v4 = *reinterpret_cast<const float4*>(vh + gofs);
                Vt[swz(c4 + 0, row)] = f2bf(v4.x);
                Vt[swz(c4 + 1, row)] = f2bf(v4.y);
                Vt[swz(c4 + 2, row)] = f2bf(v4.z);
                Vt[swz(c4 + 3, row)] = f2bf(v4.w);
            }
        }
        __syncthreads();

        // ---- S = (Q/8) K^T : 4 col-blocks x 2 k-slices ----
        f32x4 sacc[4];
        #pragma unroll
        for (int n = 0; n < 4; ++n) {
            f32x4 a = {0.f, 0.f, 0.f, 0.f};
            #pragma unroll
            for (int ks = 0; ks < 2; ++ks) {
                bf16x8 kf = *reinterpret_cast<bf16x8*>(&Ksh[swz(n * 16 + l15, ks * 32 + lg * 8)]);
                a = __builtin_amdgcn_mfma_f32_16x16x32_bf16(qf[ks], kf, a, 0, 0, 0);
            }
            sacc[n] = a;
        }

        // ---- online softmax; row r lives in 16-lane group (row = lg*4+r) ----
        float p[4][4];
        #pragma unroll
        for (int r = 0; r < 4; ++r) {
            float tm = fmaxf(fmaxf(sacc[0][r], sacc[1][r]), fmaxf(sacc[2][r], sacc[3][r]));
            #pragma unroll
            for (int off = 1; off < 16; off <<= 1)
                tm = fmaxf(tm, __shfl_xor(tm, off));

            float mnew  = fmaxf(mrow[r], tm);
            float alpha = __expf(mrow[r] - mnew);
            mrow[r] = mnew;

            float ps = 0.f;
            #pragma unroll
            for (int n = 0; n < 4; ++n) {
                float e = __expf(sacc[n][r] - mnew);
                p[n][r] = e;
                ps += e;
            }
            #pragma unroll
            for (int off = 1; off < 16; off <<= 1)
                ps += __shfl_xor(ps, off);
            lrow[r] = lrow[r] * alpha + ps;

            #pragma unroll
            for (int d = 0; d < 4; ++d) oacc[d][r] *= alpha;
        }

        // ---- P (D-layout) -> LDS -> A-layout (wave-local; no block barrier) ----
        #pragma unroll
        for (int n = 0; n < 4; ++n)
            #pragma unroll
            for (int r = 0; r < 4; ++r)
                pw[swz(lg * 4 + r, n * 16 + l15)] = f2bf(p[n][r]);
        asm volatile("s_waitcnt lgkmcnt(0)" ::: "memory");

        bf16x8 pa[2];
        #pragma unroll
        for (int ks = 0; ks < 2; ++ks)
            pa[ks] = *reinterpret_cast<bf16x8*>(&pw[swz(l15, ks * 32 + lg * 8)]);

        // ---- O += P V ----
        #pragma unroll
        for (int d = 0; d < 4; ++d) {
            #pragma unroll
            for (int ks = 0; ks < 2; ++ks) {
                bf16x8 vb = *reinterpret_cast<bf16x8*>(&Vt[swz(d * 16 + l15, ks * 32 + lg * 8)]);
                oacc[d] = __builtin_amdgcn_mfma_f32_16x16x32_bf16(pa[ks], vb, oacc[d], 0, 0, 0);
            }
        }
    }

    // ---- epilogue: normalize and store fp32 ----
    #pragma unroll
    for (int r = 0; r < 4; ++r) {
        float inv = 1.0f / lrow[r];
        float* dst = oh + (size_t)(q0 + lg * 4 + r) * DIMH;
        #pragma unroll
        for (int d = 0; d < 4; ++d)
            dst[d * 16 + l15] = oacc[d][r] * inv;
    }
}

extern "C" void kernel_launch(void* const* d_in, const int* in_sizes, int n_in,
                              void* d_out, int out_size, void* d_ws, size_t ws_size,
                              hipStream_t stream) {
    const float* q = (const float*)d_in[0];
    const float* k = (const float*)d_in[1];
    const float* v = (const float*)d_in[2];
    float* out = (float*)d_out;
    const int BHEADS = 64;                       // B*H = 4*16
    dim3 grid(BHEADS * (SEQ / QB));              // 64 * 32 = 2048 blocks
    dim3 block(256);
    fattn<<<grid, block, 0, stream>>>(q, k, v, out);
}